// Round 2
// baseline (8068.070 us; speedup 1.0000x reference)
//
#include <hip/hip_runtime.h>
#include <hip/hip_bf16.h>
#include <math.h>

// LSTM decoder, persistent-kernel design. FP16 matmul operands (3 more mantissa
// bits than bf16; h in (-1,1) and W~N(0,1/1024) are safely in fp16 range).
//   batch BS=256, input 512, hidden H=1024, T=256 steps, out (256,256,1024) fp32.
// Grid: 256 blocks = 2 batch-groups (mg) x 128 gate-slices (ng).
// Block: 256 threads = 4 waves; each wave owns 32 samples x 32 gate-cols.
// Block's W_hh slice (32 rows x 1024 k, fp16) stays in LDS (64 KB) all 256 steps.
// x_proj slice + biases live in registers as the per-step accumulator init.
// h is double-buffered fp16 in d_ws; per-step sync = per-block monotonic flags
// (release/acquire, agent scope) polled only within the same batch-group.

typedef _Float16 fp16_t;
typedef _Float16 f16x8 __attribute__((ext_vector_type(8)));
typedef float    f32x4 __attribute__((ext_vector_type(4)));

#define HID   1024
#define SEQ   256
#define BATCH 256
#define INF   512

#define MFMA(a, b, c) __builtin_amdgcn_mfma_f32_16x16x32_f16((a), (b), (c), 0, 0, 0)

__device__ __forceinline__ float sigm(float x) { return 1.0f / (1.0f + __expf(-x)); }
__device__ __forceinline__ float tanh_fast(float x) { return 1.0f - 2.0f / (__expf(2.0f * x) + 1.0f); }

__device__ __forceinline__ f16x8 cvt8(float4 lo, float4 hi) {
    f16x8 v;
    v[0] = (fp16_t)lo.x; v[1] = (fp16_t)lo.y; v[2] = (fp16_t)lo.z; v[3] = (fp16_t)lo.w;
    v[4] = (fp16_t)hi.x; v[5] = (fp16_t)hi.y; v[6] = (fp16_t)hi.z; v[7] = (fp16_t)hi.w;
    return v;
}

__global__ __launch_bounds__(256, 1) void lstm_persist(
    const float* __restrict__ ctx,   // 256 x 512
    const float* __restrict__ wih,   // 4096 x 512
    const float* __restrict__ whh,   // 4096 x 1024
    const float* __restrict__ bih,   // 4096
    const float* __restrict__ bhh,   // 4096
    float* __restrict__ out,         // 256 x 256 x 1024
    unsigned int* __restrict__ flags,// 256 (zeroed by memset before launch)
    fp16_t* __restrict__ hbuf)       // 2 x 256 x 1024 fp16 ping-pong
{
    // 32 rows x 1024 fp16 = 65536 B. XOR-swizzled at 16B-granule level so that
    // ds_read_b128 B-fragment reads are bank-uniform (floor 8 cyc / wave read).
    __shared__ __align__(16) fp16_t wlds[32 * HID];

    const int tid  = threadIdx.x;
    const int lane = tid & 63;
    const int wid  = tid >> 6;        // wave 0..3 -> 32-sample slice
    const int bid  = blockIdx.x;
    const int mg   = bid >> 7;        // 0..1   (128-sample group)
    const int ng   = bid & 127;       // 0..127 (8 hidden units)
    const int cl   = lane & 15;       // col within 16x16 tile
    const int q    = lane >> 4;       // k-quad 0..3
    const int hi   = (cl >> 3) & 1;   // 0: lane owns i,g ; 1: owns f,o
    const int nx   = cl & 7;          // swizzle key (same for both n-tiles)

    // ---- one-time: stage W_hh slice into LDS as fp16, granule-swizzled ----
    // block-local col n in [0,32): gate=(n>>3), unit = ng*8 + (n&7)
    for (int Gi = tid; Gi < 32 * 128; Gi += 256) {
        const int n = Gi >> 7, g = Gi & 127;
        const int grow = ((n >> 3) << 10) + (ng << 3) + (n & 7);
        const float4* src = reinterpret_cast<const float4*>(whh + (size_t)grow * HID + g * 8);
        float4 u0 = src[0], u1 = src[1];
        reinterpret_cast<f16x8*>(wlds)[n * 128 + (g ^ (n & 7))] = cvt8(u0, u1);
    }

    // ---- one-time: x_proj slice (= ctx @ w_ih^T + b_ih + b_hh) into registers ----
    const int rowA0 = mg * 128 + wid * 32 + cl;  // mi=0 sample row
    const int rowA1 = rowA0 + 16;                // mi=1
    const int n0 = cl, n1 = 16 + cl;             // block-local cols of the 2 n-tiles
    const int grow0 = ((n0 >> 3) << 10) + (ng << 3) + (n0 & 7);
    const int grow1 = ((n1 >> 3) << 10) + (ng << 3) + (n1 & 7);

    f32x4 x00 = {0.f, 0.f, 0.f, 0.f}, x01 = x00, x10 = x00, x11 = x00;
    {
        const float4* ca0 = reinterpret_cast<const float4*>(ctx + (size_t)rowA0 * INF);
        const float4* ca1 = reinterpret_cast<const float4*>(ctx + (size_t)rowA1 * INF);
        const float4* wb0 = reinterpret_cast<const float4*>(wih + (size_t)grow0 * INF);
        const float4* wb1 = reinterpret_cast<const float4*>(wih + (size_t)grow1 * INF);
#pragma unroll 4
        for (int kb = 0; kb < 16; ++kb) {
            const int vi = kb * 8 + q * 2;
            f16x8 a0 = cvt8(ca0[vi], ca0[vi + 1]);
            f16x8 a1 = cvt8(ca1[vi], ca1[vi + 1]);
            f16x8 b0 = cvt8(wb0[vi], wb0[vi + 1]);
            f16x8 b1 = cvt8(wb1[vi], wb1[vi + 1]);
            x00 = MFMA(a0, b0, x00); x01 = MFMA(a0, b1, x01);
            x10 = MFMA(a1, b0, x10); x11 = MFMA(a1, b1, x11);
        }
        const float bias0 = bih[grow0] + bhh[grow0];
        const float bias1 = bih[grow1] + bhh[grow1];
#pragma unroll
        for (int r = 0; r < 4; ++r) {
            x00[r] += bias0; x10[r] += bias0;
            x01[r] += bias1; x11[r] += bias1;
        }
    }
    __syncthreads();  // LDS staging complete before first B-frag read

    const f16x8* wv = reinterpret_cast<const f16x8*>(wlds);

    // epilogue write coords: this lane writes the mi==hi tile
    const int sampW = mg * 128 + wid * 32 + hi * 16 + q * 4;
    const int ug    = (ng << 3) + (cl & 7);

    f32x4 cst = {0.f, 0.f, 0.f, 0.f};  // c-state, 4 samples x 1 unit

    for (int t = 0; t < SEQ; ++t) {
        f32x4 a00 = x00, a01 = x01, a10 = x10, a11 = x11;  // acc init = x_proj

        if (t > 0) {
            // wait until every block of our batch-group published h_{t-1}
            const unsigned tgt = (unsigned)t;
            const unsigned* fb = flags + mg * 128;
            for (;;) {
                unsigned f0 = __hip_atomic_load(fb + lane,      __ATOMIC_RELAXED, __HIP_MEMORY_SCOPE_AGENT);
                unsigned f1 = __hip_atomic_load(fb + 64 + lane, __ATOMIC_RELAXED, __HIP_MEMORY_SCOPE_AGENT);
                if (__all((f0 >= tgt) && (f1 >= tgt))) break;
                __builtin_amdgcn_s_sleep(1);
            }
            __builtin_amdgcn_fence(__ATOMIC_ACQUIRE, "agent");  // invalidate stale h lines

            const fp16_t* hprev = hbuf + (size_t)((t - 1) & 1) * (BATCH * HID);
            const f16x8* pa0 = reinterpret_cast<const f16x8*>(hprev + (size_t)rowA0 * HID) + q;
            const f16x8* pa1 = reinterpret_cast<const f16x8*>(hprev + (size_t)rowA1 * HID) + q;
#pragma unroll 8
            for (int kb = 0; kb < 32; ++kb) {
                f16x8 va0 = pa0[kb * 4];           // A from L2 (h gather, 16B/lane)
                f16x8 va1 = pa1[kb * 4];
                const int gs = ((kb << 2) + q) ^ nx;
                f16x8 vb0 = wv[(cl << 7) + gs];            // B from LDS
                f16x8 vb1 = wv[(cl << 7) + gs + 2048];
                a00 = MFMA(va0, vb0, a00); a01 = MFMA(va0, vb1, a01);
                a10 = MFMA(va1, vb0, a10); a11 = MFMA(va1, vb1, a11);
            }
        }

        // ---- epilogue: pair-exchange gates, LSTM cell in fp32, stores ----
        f32x4 e00, e01, e10, e11;
#pragma unroll
        for (int r = 0; r < 4; ++r) {
            e00[r] = __shfl_xor(a00[r], 8, 64);
            e01[r] = __shfl_xor(a01[r], 8, 64);
            e10[r] = __shfl_xor(a10[r], 8, 64);
            e11[r] = __shfl_xor(a11[r], 8, 64);
        }
        // tile layout per 16 cols: [i x8 | f x8] (ni=0), [g x8 | o x8] (ni=1)
        f32x4 iv = hi ? e10 : a00;
        f32x4 fv = hi ? a10 : e00;
        f32x4 gv = hi ? e11 : a01;
        f32x4 ov = hi ? a11 : e01;

        fp16_t* hw = hbuf + (size_t)(t & 1) * (BATCH * HID) + (size_t)sampW * HID + ug;
        float*  ow = out + ((size_t)sampW * SEQ + t) * HID + ug;
#pragma unroll
        for (int r = 0; r < 4; ++r) {
            float ii = sigm(iv[r]);
            float ff = sigm(fv[r]);
            float gg = tanh_fast(gv[r]);
            float oo = sigm(ov[r]);
            float cc = ff * cst[r] + ii * gg;
            cst[r] = cc;
            float hh = oo * tanh_fast(cc);
            hw[(size_t)r * HID] = (fp16_t)hh;          // recurrent state (fp16)
            ow[(size_t)r * SEQ * HID] = hh;            // output (fp32)
        }

        __syncthreads();  // all waves' h stores drained (vmcnt) before publish
        if (tid == 0)
            __hip_atomic_store(&flags[bid], (unsigned)(t + 1),
                               __ATOMIC_RELEASE, __HIP_MEMORY_SCOPE_AGENT);
    }
}

extern "C" void kernel_launch(void* const* d_in, const int* in_sizes, int n_in,
                              void* d_out, int out_size, void* d_ws, size_t ws_size,
                              hipStream_t stream) {
    const float* ctx = (const float*)d_in[0];
    const float* wih = (const float*)d_in[1];
    const float* whh = (const float*)d_in[2];
    const float* bih = (const float*)d_in[3];
    const float* bhh = (const float*)d_in[4];
    float* out = (float*)d_out;

    // ws layout: [0,1024) flags ; [4096, 4096 + 2*512KB) fp16 h ping-pong
    unsigned int* flags = (unsigned int*)d_ws;
    fp16_t* hbuf = (fp16_t*)((char*)d_ws + 4096);

    hipMemsetAsync(d_ws, 0, 1024, stream);  // zero flags (ws re-poisoned each call)
    lstm_persist<<<dim3(256), dim3(256), 0, stream>>>(ctx, wih, whh, bih, bhh,
                                                      out, flags, hbuf);
}

// Round 4
// 7602.097 us; speedup vs baseline: 1.0613x; 1.0613x over previous
//
#include <hip/hip_runtime.h>
#include <hip/hip_bf16.h>
#include <math.h>

// LSTM decoder, persistent fence-free design (R2 shape + fence-free transport).
//   batch 256, input 512, hidden H=1024, T=256 steps, out (256,256,1024) fp32.
// Grid: 256 blocks = 2 batch-groups (mg, 128 samples) x 128 gate-slices (ng).
// Block: 256 threads = 4 waves; each wave owns 32 samples x 32 gate-cols.
// W_hh slice (32 cols x 1024 k fp16 = 64 KB) resident in LDS all 256 steps.
// h transport = the fp32 output buffer itself (write-once addresses -> no
// stale-cache hazard -> NO per-step fences):
//   producers: agent-scope relaxed atomic stores (write-through, no fence)
//   consumers: normal cached loads (L2 shares h lines across same-XCD blocks)
// Per-step sync: per-block monotonic flags, relaxed agent atomics only.

typedef _Float16 fp16_t;
typedef _Float16 f16x8 __attribute__((ext_vector_type(8)));
typedef float    f32x4 __attribute__((ext_vector_type(4)));

#define HID   1024
#define SEQ   256
#define INF   512

#define MFMA(a, b, c) __builtin_amdgcn_mfma_f32_16x16x32_f16((a), (b), (c), 0, 0, 0)

__device__ __forceinline__ float sigm(float x) { return 1.0f / (1.0f + __expf(-x)); }
__device__ __forceinline__ float tanh_fast(float x) { return 1.0f - 2.0f / (__expf(2.0f * x) + 1.0f); }

__device__ __forceinline__ f16x8 cvt8(float4 lo, float4 hi) {
    f16x8 v;
    v[0] = (fp16_t)lo.x; v[1] = (fp16_t)lo.y; v[2] = (fp16_t)lo.z; v[3] = (fp16_t)lo.w;
    v[4] = (fp16_t)hi.x; v[5] = (fp16_t)hi.y; v[6] = (fp16_t)hi.z; v[7] = (fp16_t)hi.w;
    return v;
}

__global__ __launch_bounds__(256, 1) void lstm_persist(
    const float* __restrict__ ctx,   // 256 x 512
    const float* __restrict__ wih,   // 4096 x 512
    const float* __restrict__ whh,   // 4096 x 1024
    const float* __restrict__ bih,   // 4096
    const float* __restrict__ bhh,   // 4096
    float* __restrict__ out,         // 256 x 256 x 1024 (also the h transport)
    unsigned int* __restrict__ flags)// 256 (zeroed before launch)
{
    // 32 cols x 1024 k fp16 = 65536 B, 16B-granule XOR swizzle (conflict-free
    // ds_read_b128 B-fragment reads).
    __shared__ __align__(16) fp16_t wlds[32 * HID];

    const int tid  = threadIdx.x;
    const int lane = tid & 63;
    const int wid  = tid >> 6;        // wave 0..3 -> 32-sample slice
    const int bid  = blockIdx.x;
    const int mg   = bid >> 7;        // 0..1   (128-sample group)
    const int ng   = bid & 127;       // 0..127 (8 hidden units)
    const int cl   = lane & 15;       // col within 16x16 tile
    const int q    = lane >> 4;       // k-quad 0..3
    const int hi   = (cl >> 3) & 1;   // 0: lane owns i,g ; 1: owns f,o
    const int nx   = cl & 7;          // swizzle key

    // ---- one-time: stage W_hh slice into LDS as fp16, granule-swizzled ----
    // block-local col n in [0,32): gate=(n>>3), unit = ng*8 + (n&7)
    for (int Gi = tid; Gi < 32 * 128; Gi += 256) {
        const int n = Gi >> 7, g = Gi & 127;
        const int grow = ((n >> 3) << 10) + (ng << 3) + (n & 7);
        const float4* src = reinterpret_cast<const float4*>(whh + (size_t)grow * HID + g * 8);
        float4 u0 = src[0], u1 = src[1];
        reinterpret_cast<f16x8*>(wlds)[n * 128 + (g ^ (n & 7))] = cvt8(u0, u1);
    }

    // ---- one-time: x_proj slice (= ctx @ w_ih^T + b_ih + b_hh) into registers ----
    const int rowA0 = mg * 128 + wid * 32 + cl;  // mi=0 sample row
    const int rowA1 = rowA0 + 16;                // mi=1
    const int n0 = cl, n1 = 16 + cl;             // block-local cols of the 2 n-tiles
    const int grow0 = ((n0 >> 3) << 10) + (ng << 3) + (n0 & 7);
    const int grow1 = ((n1 >> 3) << 10) + (ng << 3) + (n1 & 7);

    f32x4 x00 = {0.f, 0.f, 0.f, 0.f}, x01 = x00, x10 = x00, x11 = x00;
    {
        const float4* ca0 = reinterpret_cast<const float4*>(ctx + (size_t)rowA0 * INF);
        const float4* ca1 = reinterpret_cast<const float4*>(ctx + (size_t)rowA1 * INF);
        const float4* wb0 = reinterpret_cast<const float4*>(wih + (size_t)grow0 * INF);
        const float4* wb1 = reinterpret_cast<const float4*>(wih + (size_t)grow1 * INF);
#pragma unroll 4
        for (int kb = 0; kb < 16; ++kb) {
            const int vi = kb * 8 + q * 2;
            f16x8 a0 = cvt8(ca0[vi], ca0[vi + 1]);
            f16x8 a1 = cvt8(ca1[vi], ca1[vi + 1]);
            f16x8 b0 = cvt8(wb0[vi], wb0[vi + 1]);
            f16x8 b1 = cvt8(wb1[vi], wb1[vi + 1]);
            x00 = MFMA(a0, b0, x00); x01 = MFMA(a0, b1, x01);
            x10 = MFMA(a1, b0, x10); x11 = MFMA(a1, b1, x11);
        }
        const float bias0 = bih[grow0] + bhh[grow0];
        const float bias1 = bih[grow1] + bhh[grow1];
#pragma unroll
        for (int r = 0; r < 4; ++r) {
            x00[r] += bias0; x10[r] += bias0;
            x01[r] += bias1; x11[r] += bias1;
        }
    }
    __syncthreads();  // LDS staging complete before first B-frag read

    const f16x8* wv = reinterpret_cast<const f16x8*>(wlds);

    // epilogue write coords: this lane writes the mi==hi tile
    const int sampW = mg * 128 + wid * 32 + hi * 16 + q * 4;
    const int ug    = (ng << 3) + (cl & 7);

    f32x4 cst = {0.f, 0.f, 0.f, 0.f};  // c-state, 4 samples x 1 unit

    for (int t = 0; t < SEQ; ++t) {
        f32x4 a00 = x00, a01 = x01, a10 = x10, a11 = x11;  // acc init = x_proj

        if (t > 0) {
            // wait until every block of our batch-group published h_{t-1}
            const unsigned tgt = (unsigned)t;
            const unsigned* fb = flags + mg * 128;
            for (;;) {
                unsigned f0 = __hip_atomic_load(fb + lane,      __ATOMIC_RELAXED, __HIP_MEMORY_SCOPE_AGENT);
                unsigned f1 = __hip_atomic_load(fb + 64 + lane, __ATOMIC_RELAXED, __HIP_MEMORY_SCOPE_AGENT);
                if (__all((f0 >= tgt) && (f1 >= tgt))) break;
                __builtin_amdgcn_s_sleep(1);
            }
            asm volatile("" ::: "memory");  // no load hoisting above the poll
            // NOTE: no acquire fence — h addresses are write-once this kernel,
            // so consumer L2 cannot hold a stale copy; skipping the fence keeps
            // L2 warm (the R2 per-step invalidate was the 8 ms bottleneck).

            // h_{t-1} straight from out (fp32, normal cached loads)
            const float4* pa0 = reinterpret_cast<const float4*>(out + ((size_t)rowA0 * SEQ + (t - 1)) * HID);
            const float4* pa1 = reinterpret_cast<const float4*>(out + ((size_t)rowA1 * SEQ + (t - 1)) * HID);
#pragma unroll 8
            for (int kb = 0; kb < 32; ++kb) {
                const int vi = kb * 8 + q * 2;
                f16x8 va0 = cvt8(pa0[vi], pa0[vi + 1]);
                f16x8 va1 = cvt8(pa1[vi], pa1[vi + 1]);
                const int gs = ((kb << 2) + q) ^ nx;
                f16x8 vb0 = wv[(cl << 7) + gs];            // B from LDS
                f16x8 vb1 = wv[(cl << 7) + gs + 2048];
                a00 = MFMA(va0, vb0, a00); a01 = MFMA(va0, vb1, a01);
                a10 = MFMA(va1, vb0, a10); a11 = MFMA(va1, vb1, a11);
            }
        }

        // ---- epilogue: pair-exchange gates, LSTM cell in fp32, publish ----
        f32x4 e00, e01, e10, e11;
#pragma unroll
        for (int r = 0; r < 4; ++r) {
            e00[r] = __shfl_xor(a00[r], 8, 64);
            e01[r] = __shfl_xor(a01[r], 8, 64);
            e10[r] = __shfl_xor(a10[r], 8, 64);
            e11[r] = __shfl_xor(a11[r], 8, 64);
        }
        // tile layout per 16 cols: [i x8 | f x8] (ni=0), [g x8 | o x8] (ni=1)
        f32x4 iv = hi ? e10 : a00;
        f32x4 fv = hi ? a10 : e00;
        f32x4 gv = hi ? e11 : a01;
        f32x4 ov = hi ? a11 : e01;

        float* ow = out + ((size_t)sampW * SEQ + t) * HID + ug;
#pragma unroll
        for (int r = 0; r < 4; ++r) {
            float ii = sigm(iv[r]);
            float ff = sigm(fv[r]);
            float gg = tanh_fast(gv[r]);
            float oo = sigm(ov[r]);
            float cc = ff * cst[r] + ii * gg;
            cst[r] = cc;
            float hh = oo * tanh_fast(cc);
            // agent-scope relaxed store: write-through past L2, no fence
            __hip_atomic_store(ow + (size_t)r * SEQ * HID, hh,
                               __ATOMIC_RELAXED, __HIP_MEMORY_SCOPE_AGENT);
        }

        __syncthreads();  // drains all waves' vmcnt before flag publish
        if (tid == 0)
            __hip_atomic_store(&flags[bid], (unsigned)(t + 1),
                               __ATOMIC_RELAXED, __HIP_MEMORY_SCOPE_AGENT);
    }
}

extern "C" void kernel_launch(void* const* d_in, const int* in_sizes, int n_in,
                              void* d_out, int out_size, void* d_ws, size_t ws_size,
                              hipStream_t stream) {
    const float* ctx = (const float*)d_in[0];
    const float* wih = (const float*)d_in[1];
    const float* whh = (const float*)d_in[2];
    const float* bih = (const float*)d_in[3];
    const float* bhh = (const float*)d_in[4];
    float* out = (float*)d_out;

    unsigned int* flags = (unsigned int*)d_ws;  // 256 x u32
    hipMemsetAsync(d_ws, 0, 1024, stream);      // zero flags (ws re-poisoned each call)
    lstm_persist<<<dim3(256), dim3(256), 0, stream>>>(ctx, wih, whh, bih, bhh,
                                                      out, flags);
}

// Round 5
// 5561.751 us; speedup vs baseline: 1.4506x; 1.3669x over previous
//
#include <hip/hip_runtime.h>
#include <hip/hip_bf16.h>
#include <math.h>

// LSTM decoder, persistent design, LLC-resident h transport.
//   batch 256, input 512, hidden H=1024, T=256 steps, out (256,256,1024) fp32.
// Grid: 256 blocks = 2 batch-groups (mg, 128 samples) x 128 gate-slices (ng).
// W_hh slice (32 cols x 1024 k fp16 = 64 KB) resident in LDS all 256 steps.
// h transport = the fp32 out buffer itself, PUBLISHED VIA RELAXED AGENT-SCOPE
// ATOMIC EXCHANGE: device-scope RMWs execute at the MALL (Infinity Cache), so
// h allocates dirty in LLC -> consumer loads hit LLC (~550cyc), not DRAM
// (~900cyc). R4's sc1 write-through streamed to DRAM (FETCH_SIZE 1.07 GB).
// Flags likewise atomic-exchange -> polls hit LLC. Only wave 0 polls.
// Consumer h loads: normal cached loads (addresses are write-once -> no
// stale-line hazard), 2-stage software pipeline for MLP.

typedef _Float16 fp16_t;
typedef _Float16 f16x8 __attribute__((ext_vector_type(8)));
typedef float    f32x4 __attribute__((ext_vector_type(4)));

#define HID   1024
#define SEQ   256
#define INF   512

#define MFMA(a, b, c) __builtin_amdgcn_mfma_f32_16x16x32_f16((a), (b), (c), 0, 0, 0)

__device__ __forceinline__ float sigm(float x) { return 1.0f / (1.0f + __expf(-x)); }
__device__ __forceinline__ float tanh_fast(float x) { return 1.0f - 2.0f / (__expf(2.0f * x) + 1.0f); }

__device__ __forceinline__ f16x8 cvt8(float4 lo, float4 hi) {
    f16x8 v;
    v[0] = (fp16_t)lo.x; v[1] = (fp16_t)lo.y; v[2] = (fp16_t)lo.z; v[3] = (fp16_t)lo.w;
    v[4] = (fp16_t)hi.x; v[5] = (fp16_t)hi.y; v[6] = (fp16_t)hi.z; v[7] = (fp16_t)hi.w;
    return v;
}

__global__ __launch_bounds__(256, 1) void lstm_persist(
    const float* __restrict__ ctx,   // 256 x 512
    const float* __restrict__ wih,   // 4096 x 512
    const float* __restrict__ whh,   // 4096 x 1024
    const float* __restrict__ bih,   // 4096
    const float* __restrict__ bhh,   // 4096
    float* __restrict__ out,         // 256 x 256 x 1024 (also the h transport)
    unsigned int* __restrict__ flags)// 256 (zeroed before launch)
{
    __shared__ __align__(16) fp16_t wlds[32 * HID];

    const int tid  = threadIdx.x;
    const int lane = tid & 63;
    const int wid  = tid >> 6;        // wave 0..3 -> 32-sample slice
    const int bid  = blockIdx.x;
    const int mg   = bid >> 7;        // 0..1   (128-sample group)
    const int ng   = bid & 127;       // 0..127 (8 hidden units)
    const int cl   = lane & 15;       // col within 16x16 tile
    const int q    = lane >> 4;       // k-quad 0..3
    const int hi   = (cl >> 3) & 1;   // 0: lane owns i,g ; 1: owns f,o
    const int nx   = cl & 7;          // swizzle key
    const int rot  = ng & 31;         // per-block k-rotation (spread MALL slices)

    // ---- one-time: stage W_hh slice into LDS as fp16, granule-swizzled ----
    for (int Gi = tid; Gi < 32 * 128; Gi += 256) {
        const int n = Gi >> 7, g = Gi & 127;
        const int grow = ((n >> 3) << 10) + (ng << 3) + (n & 7);
        const float4* src = reinterpret_cast<const float4*>(whh + (size_t)grow * HID + g * 8);
        float4 u0 = src[0], u1 = src[1];
        reinterpret_cast<f16x8*>(wlds)[n * 128 + (g ^ (n & 7))] = cvt8(u0, u1);
    }

    // ---- one-time: x_proj slice (= ctx @ w_ih^T + b_ih + b_hh) ----
    const int rowA0 = mg * 128 + wid * 32 + cl;  // mi=0 sample row
    const int rowA1 = rowA0 + 16;                // mi=1
    const int n0 = cl, n1 = 16 + cl;
    const int grow0 = ((n0 >> 3) << 10) + (ng << 3) + (n0 & 7);
    const int grow1 = ((n1 >> 3) << 10) + (ng << 3) + (n1 & 7);

    f32x4 x00 = {0.f, 0.f, 0.f, 0.f}, x01 = x00, x10 = x00, x11 = x00;
    {
        const float4* ca0 = reinterpret_cast<const float4*>(ctx + (size_t)rowA0 * INF);
        const float4* ca1 = reinterpret_cast<const float4*>(ctx + (size_t)rowA1 * INF);
        const float4* wb0 = reinterpret_cast<const float4*>(wih + (size_t)grow0 * INF);
        const float4* wb1 = reinterpret_cast<const float4*>(wih + (size_t)grow1 * INF);
#pragma unroll 4
        for (int kb = 0; kb < 16; ++kb) {
            const int vi = kb * 8 + q * 2;
            f16x8 a0 = cvt8(ca0[vi], ca0[vi + 1]);
            f16x8 a1 = cvt8(ca1[vi], ca1[vi + 1]);
            f16x8 b0 = cvt8(wb0[vi], wb0[vi + 1]);
            f16x8 b1 = cvt8(wb1[vi], wb1[vi + 1]);
            x00 = MFMA(a0, b0, x00); x01 = MFMA(a0, b1, x01);
            x10 = MFMA(a1, b0, x10); x11 = MFMA(a1, b1, x11);
        }
        const float bias0 = bih[grow0] + bhh[grow0];
        const float bias1 = bih[grow1] + bhh[grow1];
#pragma unroll
        for (int r = 0; r < 4; ++r) {
            x00[r] += bias0; x10[r] += bias0;
            x01[r] += bias1; x11[r] += bias1;
        }
    }
    __syncthreads();  // LDS staging complete

    const f16x8* wv = reinterpret_cast<const f16x8*>(wlds);

    const int sampW = mg * 128 + wid * 32 + hi * 16 + q * 4;
    const int ug    = (ng << 3) + (cl & 7);

    f32x4 cst = {0.f, 0.f, 0.f, 0.f};  // c-state

    for (int t = 0; t < SEQ; ++t) {
        f32x4 a00 = x00, a01 = x01, a10 = x10, a11 = x11;

        if (t > 0) {
            // wave 0 polls the 128 flags of our batch-group (flags live in MALL)
            if (wid == 0) {
                const unsigned tgt = (unsigned)t;
                const unsigned* fb = flags + mg * 128;
                for (;;) {
                    unsigned f0 = __hip_atomic_load(fb + lane,      __ATOMIC_RELAXED, __HIP_MEMORY_SCOPE_AGENT);
                    unsigned f1 = __hip_atomic_load(fb + 64 + lane, __ATOMIC_RELAXED, __HIP_MEMORY_SCOPE_AGENT);
                    if (__all((f0 >= tgt) && (f1 >= tgt))) break;
                    __builtin_amdgcn_s_sleep(1);
                }
            }
            __syncthreads();   // releases waves 1-3; orders loads after poll
            asm volatile("" ::: "memory");

            // h_{t-1} from out: normal cached loads (write-once addresses),
            // data resident in MALL thanks to atomic-exchange publication.
            const float4* pa0 = reinterpret_cast<const float4*>(out + ((size_t)rowA0 * SEQ + (t - 1)) * HID);
            const float4* pa1 = reinterpret_cast<const float4*>(out + ((size_t)rowA1 * SEQ + (t - 1)) * HID);

            // 2-stage software pipeline over 32 k-blocks (rotated per block)
            int cur = rot;
            float4 c00 = pa0[cur * 8 + q * 2], c01 = pa0[cur * 8 + q * 2 + 1];
            float4 c10 = pa1[cur * 8 + q * 2], c11 = pa1[cur * 8 + q * 2 + 1];
#pragma unroll 8
            for (int kb = 0; kb < 32; ++kb) {
                float4 d00, d01, d10, d11;
                if (kb < 31) {
                    const int nxt = (kb + 1 + rot) & 31;
                    d00 = pa0[nxt * 8 + q * 2]; d01 = pa0[nxt * 8 + q * 2 + 1];
                    d10 = pa1[nxt * 8 + q * 2]; d11 = pa1[nxt * 8 + q * 2 + 1];
                }
                f16x8 va0 = cvt8(c00, c01);
                f16x8 va1 = cvt8(c10, c11);
                const int gs = ((cur << 2) + q) ^ nx;
                f16x8 vb0 = wv[(cl << 7) + gs];
                f16x8 vb1 = wv[(cl << 7) + gs + 2048];
                a00 = MFMA(va0, vb0, a00); a01 = MFMA(va0, vb1, a01);
                a10 = MFMA(va1, vb0, a10); a11 = MFMA(va1, vb1, a11);
                c00 = d00; c01 = d01; c10 = d10; c11 = d11;
                cur = (kb + 1 + rot) & 31;
            }
        }

        // ---- epilogue: pair-exchange gates, LSTM cell fp32, publish ----
        f32x4 e00, e01, e10, e11;
#pragma unroll
        for (int r = 0; r < 4; ++r) {
            e00[r] = __shfl_xor(a00[r], 8, 64);
            e01[r] = __shfl_xor(a01[r], 8, 64);
            e10[r] = __shfl_xor(a10[r], 8, 64);
            e11[r] = __shfl_xor(a11[r], 8, 64);
        }
        f32x4 iv = hi ? e10 : a00;
        f32x4 fv = hi ? a10 : e00;
        f32x4 gv = hi ? e11 : a01;
        f32x4 ov = hi ? a11 : e01;

        unsigned* ow = reinterpret_cast<unsigned*>(out + ((size_t)sampW * SEQ + t) * HID + ug);
#pragma unroll
        for (int r = 0; r < 4; ++r) {
            float ii = sigm(iv[r]);
            float ff = sigm(fv[r]);
            float gg = tanh_fast(gv[r]);
            float oo = sigm(ov[r]);
            float cc = ff * cst[r] + ii * gg;
            cst[r] = cc;
            float hh = oo * tanh_fast(cc);
            // atomic exchange = RMW at the MALL -> h allocates in LLC
            __hip_atomic_exchange(ow + (size_t)r * SEQ * HID,
                                  __builtin_bit_cast(unsigned, hh),
                                  __ATOMIC_RELAXED, __HIP_MEMORY_SCOPE_AGENT);
        }

        __syncthreads();  // drains all waves' vmcnt before flag publish
        if (tid == 0)
            __hip_atomic_exchange(&flags[bid], (unsigned)(t + 1),
                                  __ATOMIC_RELAXED, __HIP_MEMORY_SCOPE_AGENT);
    }
}

extern "C" void kernel_launch(void* const* d_in, const int* in_sizes, int n_in,
                              void* d_out, int out_size, void* d_ws, size_t ws_size,
                              hipStream_t stream) {
    const float* ctx = (const float*)d_in[0];
    const float* wih = (const float*)d_in[1];
    const float* whh = (const float*)d_in[2];
    const float* bih = (const float*)d_in[3];
    const float* bhh = (const float*)d_in[4];
    float* out = (float*)d_out;

    unsigned int* flags = (unsigned int*)d_ws;  // 256 x u32
    hipMemsetAsync(d_ws, 0, 1024, stream);      // zero flags
    lstm_persist<<<dim3(256), dim3(256), 0, stream>>>(ctx, wih, whh, bih, bhh,
                                                      out, flags);
}